// Round 1
// baseline (4266.208 us; speedup 1.0000x reference)
//
#include <hip/hip_runtime.h>
#include <hip/hip_bf16.h>

// TensorizedRNN: m1/m2 = einsum('bj,bk,ljk->bl', h, x, W{1,2}) as bf16-MFMA GEMM
// with virtual A = h (outer) x, K = 1024*256 = 262144.
// B=1024, I2=256, H=512, N=1024 (W1||W2), J=1024.

typedef __attribute__((ext_vector_type(8))) short short8;
typedef __attribute__((ext_vector_type(4))) float f32x4;
typedef unsigned short ushort_t;

#define GLL16(gp, lp)                                                          \
  __builtin_amdgcn_global_load_lds(                                            \
      (const __attribute__((address_space(1))) void*)(gp),                     \
      (__attribute__((address_space(3))) void*)(lp), 16, 0, 0)

__device__ __forceinline__ unsigned pkbf(float a, float b) {
  __hip_bfloat162 h2 = __float22bfloat162_rn(make_float2(a, b));
  union { __hip_bfloat162 h; unsigned u; } cv;
  cv.h = h2;
  return cv.u;  // low16 = a, high16 = b
}

__device__ __forceinline__ ushort_t f2bu(float f) {
  __hip_bfloat16 b = __float2bfloat16(f);
  union { __hip_bfloat16 b; ushort_t u; } cv;
  cv.b = b;
  return cv.u;
}

// ---------------- prep: hb16[b][j], xb16[b][kx], WmergeT[l][j] (all bf16) ---
__global__ void prep_k(const float* __restrict__ in0, const float* __restrict__ in1,
                       const float* __restrict__ s0, const float* __restrict__ s1,
                       const float* __restrict__ Wm,
                       ushort_t* __restrict__ hb, ushort_t* __restrict__ xb,
                       ushort_t* __restrict__ WmT) {
  __shared__ float tl[64][65];
  const int bid = blockIdx.x, t = threadIdx.x;
  if (bid < 256) {  // hb16: 1M elems, 4096/block
#pragma unroll
    for (int i = 0; i < 4; ++i) {
      int e = bid * 4096 + i * 1024 + t * 4;
      int b = e >> 10, j = e & 1023;
      const float* src = (j < 512) ? (s0 + (size_t)b * 512 + j)
                                   : (s1 + (size_t)b * 512 + j - 512);
      float4 v = *(const float4*)src;
      ushort4 o;
      o.x = f2bu(v.x); o.y = f2bu(v.y); o.z = f2bu(v.z); o.w = f2bu(v.w);
      *(ushort4*)(hb + e) = o;
    }
  } else if (bid < 272) {  // xb16: 256K elems, 16384/block
#pragma unroll
    for (int i = 0; i < 16; ++i) {
      int e = (bid - 256) * 16384 + i * 1024 + t * 4;
      int b = e >> 8, kx = e & 255;
      const float* src = (kx < 128) ? (in0 + (size_t)b * 128 + kx)
                                    : (in1 + (size_t)b * 128 + kx - 128);
      float4 v = *(const float4*)src;
      ushort4 o;
      o.x = f2bu(v.x); o.y = f2bu(v.y); o.z = f2bu(v.z); o.w = f2bu(v.w);
      *(ushort4*)(xb + e) = o;
    }
  } else {  // Wmerge [1024][512] -> WmT [512][1024], 64x64 tiles
    int q = bid - 272;           // 0..127
    int j0 = (q >> 3) * 64;
    int l0 = (q & 7) * 64;
#pragma unroll
    for (int i = 0; i < 16; ++i) {
      int idx = i * 256 + t; int r = idx >> 6, c = idx & 63;
      tl[r][c] = Wm[(size_t)(j0 + r) * 512 + l0 + c];
    }
    __syncthreads();
#pragma unroll
    for (int i = 0; i < 16; ++i) {
      int idx = i * 256 + t; int r = idx >> 6, c = idx & 63;
      WmT[(size_t)(l0 + r) * 1024 + j0 + c] = f2bu(tl[c][r]);
    }
  }
}

// ---------------- main bilinear GEMM --------------------------------------
// grid (16 ntiles, 16 kchunks), 512 threads (8 waves).
// Block: all 1024 batch rows x 64 n-cols; K-chunk = 512 j's x 32 kx's.
// LDS: W f32 tile [64 col][8 jsub][32 kx], double buffered = 128 KB,
// filled by global_load_lds w/ source-side chunk-XOR swizzle.
__global__ __launch_bounds__(512, 2) void bilin_k(
    const float* __restrict__ W1, const float* __restrict__ W2,
    const ushort_t* __restrict__ hb, const ushort_t* __restrict__ xb,
    float* __restrict__ accg) {
  __shared__ float Bl[2][16384];  // 2 x 64 KB

  const int ntile = blockIdx.x;         // 0..15 -> n cols ntile*64..+63
  const int chunk = blockIdx.y;         // 0..15
  const int kxwin = (chunk & 7) * 32;   // kx window
  const int jbase0 = (chunk >> 3) * 512;
  const int tid = threadIdx.x;
  const int wave = tid >> 6;
  const int lane = tid & 63;
  const int l15 = lane & 15;
  const int lg = lane >> 4;
  const int wrow = wave * 128;          // wave's 128 batch rows
  const int jsg = lane >> 3;            // gll: j-sub handled by this lane
  const int slot = lane & 7;            // gll: 16B slot within 32-kx run

  const float* Wsel = (ntile < 8) ? W1 : W2;
  const float* Wbase = Wsel + (size_t)(ntile & 7) * 64 * 262144;

  // per-lane x cache: 8 bf16 per M-group (j-invariant)
  uint4 xc[8];
#pragma unroll
  for (int g = 0; g < 8; ++g)
    xc[g] = *(const uint4*)(xb + (size_t)(wrow + g * 16 + l15) * 256 + kxwin + lg * 8);

  f32x4 acc[8][4];
  const f32x4 z4 = {0.f, 0.f, 0.f, 0.f};
#pragma unroll
  for (int g = 0; g < 8; ++g)
#pragma unroll
    for (int nc = 0; nc < 4; ++nc) acc[g][nc] = z4;

  // prologue: stage 0
  {
    float* dst = &Bl[0][0];
#pragma unroll
    for (int i = 0; i < 8; ++i) {
      int col = wave * 8 + i;
      const float* gp = Wbase + (size_t)col * 262144 +
                        (size_t)(jbase0 + jsg) * 256 + kxwin +
                        ((slot ^ (col & 7)) << 2);
      GLL16(gp, dst + col * 256);
    }
  }
  __syncthreads();

  for (int t = 0; t < 64; ++t) {
    const int jbase = jbase0 + t * 8;
    // h for this stage: 8 consecutive j per row, packed bf16
    uint4 hc[8];
#pragma unroll
    for (int g = 0; g < 8; ++g)
      hc[g] = *(const uint4*)(hb + (size_t)(wrow + g * 16 + l15) * 1024 + jbase);

    // prefetch next W tile (flies during compute; drained by syncthreads)
    if (t + 1 < 64) {
      float* dst = &Bl[(t + 1) & 1][0];
      const int jb2 = jbase + 8;
#pragma unroll
      for (int i = 0; i < 8; ++i) {
        int col = wave * 8 + i;
        const float* gp = Wbase + (size_t)col * 262144 +
                          (size_t)(jb2 + jsg) * 256 + kxwin +
                          ((slot ^ (col & 7)) << 2);
        GLL16(gp, dst + col * 256);
      }
    }

    const float* bp = &Bl[t & 1][0];
#pragma unroll
    for (int js = 0; js < 8; ++js) {
      // B fragments: f32 from LDS (swizzled), cvt to bf16
      short8 bfr[4];
#pragma unroll
      for (int nc = 0; nc < 4; ++nc) {
        int col = nc * 16 + l15;
        int swz = col & 7;
        int base = col * 256 + js * 32;
        float4 va = *(const float4*)(bp + base + (((lg * 2 + 0) ^ swz) << 2));
        float4 vb = *(const float4*)(bp + base + (((lg * 2 + 1) ^ swz) << 2));
        union { unsigned u[4]; short8 s; } cv;
        cv.u[0] = pkbf(va.x, va.y); cv.u[1] = pkbf(va.z, va.w);
        cv.u[2] = pkbf(vb.x, vb.y); cv.u[3] = pkbf(vb.z, vb.w);
        bfr[nc] = cv.s;
      }
#pragma unroll
      for (int g = 0; g < 8; ++g) {
        unsigned hw = (js < 2) ? hc[g].x : (js < 4) ? hc[g].y
                     : (js < 6) ? hc[g].z : hc[g].w;
        float hf = __uint_as_float((js & 1) ? (hw & 0xFFFF0000u) : (hw << 16));
        // A fragment: bf16(h * x), 8 elems
        unsigned xw[4] = {xc[g].x, xc[g].y, xc[g].z, xc[g].w};
        union { unsigned u[4]; short8 s; } av;
#pragma unroll
        for (int p = 0; p < 4; ++p) {
          float lo = __uint_as_float(xw[p] << 16);
          float hi = __uint_as_float(xw[p] & 0xFFFF0000u);
          av.u[p] = pkbf(hf * lo, hf * hi);
        }
        short8 afr = av.s;
#pragma unroll
        for (int nc = 0; nc < 4; ++nc)
          acc[g][nc] = __builtin_amdgcn_mfma_f32_16x16x32_bf16(
              afr, bfr[nc], acc[g][nc], 0, 0, 0);
      }
    }
    __syncthreads();
  }

  // epilogue: split-K accumulate (16 adds per output elem over whole grid)
#pragma unroll
  for (int g = 0; g < 8; ++g)
#pragma unroll
    for (int nc = 0; nc < 4; ++nc)
#pragma unroll
      for (int r = 0; r < 4; ++r) {
        int b = wrow + g * 16 + lg * 4 + r;
        int n = ntile * 64 + nc * 16 + l15;
        unsafeAtomicAdd(&accg[(size_t)b * 1024 + n], acc[g][nc][r]);
      }
}

// ---------------- merge = h @ Wmerge (1024x512x1024 bf16 MFMA) -------------
__device__ __forceinline__ short8 ld8bf(const ushort_t* p) {
  union { uint4 v; short8 s; } cv;
  cv.v = *(const uint4*)p;
  return cv.s;
}

__global__ __launch_bounds__(256) void merge_k(const ushort_t* __restrict__ hb,
                                               const ushort_t* __restrict__ WmT,
                                               float* __restrict__ mout) {
  const int tid = threadIdx.x;
  const int wave = tid >> 6, lane = tid & 63;
  const int l15 = lane & 15, lg = lane >> 4;
  const int m0 = blockIdx.x * 64 + (wave >> 1) * 32;
  const int n0 = blockIdx.y * 64 + (wave & 1) * 32;
  const f32x4 z4 = {0.f, 0.f, 0.f, 0.f};
  f32x4 acc[2][2];
#pragma unroll
  for (int g = 0; g < 2; ++g)
#pragma unroll
    for (int nc = 0; nc < 2; ++nc) acc[g][nc] = z4;

  for (int k = 0; k < 1024; k += 32) {
    short8 af[2], bf[2];
#pragma unroll
    for (int g = 0; g < 2; ++g)
      af[g] = ld8bf(hb + (size_t)(m0 + g * 16 + l15) * 1024 + k + lg * 8);
#pragma unroll
    for (int nc = 0; nc < 2; ++nc)
      bf[nc] = ld8bf(WmT + (size_t)(n0 + nc * 16 + l15) * 1024 + k + lg * 8);
#pragma unroll
    for (int g = 0; g < 2; ++g)
#pragma unroll
      for (int nc = 0; nc < 2; ++nc)
        acc[g][nc] = __builtin_amdgcn_mfma_f32_16x16x32_bf16(
            af[g], bf[nc], acc[g][nc], 0, 0, 0);
  }
#pragma unroll
  for (int g = 0; g < 2; ++g)
#pragma unroll
    for (int nc = 0; nc < 2; ++nc)
#pragma unroll
      for (int r = 0; r < 4; ++r)
        mout[(size_t)(m0 + g * 16 + lg * 4 + r) * 512 + n0 + nc * 16 + l15] =
            acc[g][nc][r];
}

// ---------------- finalize -------------------------------------------------
__global__ void fin_k(const float* __restrict__ accg, const float* __restrict__ mout,
                      const float* __restrict__ b1, const float* __restrict__ b2,
                      float* __restrict__ out) {
  int idx = blockIdx.x * 256 + threadIdx.x;  // 524288 total
  int b = idx >> 9, l = idx & 511;
  float m1 = accg[(size_t)b * 1024 + l];
  float m2 = accg[(size_t)b * 1024 + 512 + l];
  float st = tanhf(m1 + b1[l]);
  float u = 1.f / (1.f + expf(-(m2 + b2[l])));
  out[idx] = u * st + (1.f - u) * mout[idx];
}

extern "C" void kernel_launch(void* const* d_in, const int* in_sizes, int n_in,
                              void* d_out, int out_size, void* d_ws, size_t ws_size,
                              hipStream_t stream) {
  const float* in0 = (const float*)d_in[0];
  const float* in1 = (const float*)d_in[1];
  const float* s0  = (const float*)d_in[2];
  const float* s1  = (const float*)d_in[3];
  const float* W1  = (const float*)d_in[4];
  const float* b1  = (const float*)d_in[5];
  const float* W2  = (const float*)d_in[6];
  const float* b2  = (const float*)d_in[7];
  const float* Wm  = (const float*)d_in[8];
  float* out = (float*)d_out;

  char* ws = (char*)d_ws;
  float*    accg = (float*)(ws + 0);                          // 4 MB
  float*    mout = (float*)(ws + (4u << 20));                 // 2 MB
  ushort_t* hb   = (ushort_t*)(ws + (6u << 20));              // 2 MB
  ushort_t* xb   = (ushort_t*)(ws + (8u << 20));              // 512 KB
  ushort_t* WmT  = (ushort_t*)(ws + (8u << 20) + (512u << 10)); // 1 MB

  hipMemsetAsync(accg, 0, 4u << 20, stream);
  prep_k<<<400, 256, 0, stream>>>(in0, in1, s0, s1, Wm, hb, xb, WmT);
  bilin_k<<<dim3(16, 16), 512, 0, stream>>>(W1, W2, hb, xb, accg);
  merge_k<<<dim3(16, 8), 256, 0, stream>>>(hb, WmT, mout);
  fin_k<<<2048, 256, 0, stream>>>(accg, mout, b1, b2, out);
}

// Round 2
// 4154.292 us; speedup vs baseline: 1.0269x; 1.0269x over previous
//
#include <hip/hip_runtime.h>
#include <hip/hip_bf16.h>

// TensorizedRNN: m1/m2 = einsum('bj,bk,ljk->bl', h, x, W{1,2}) as bf16-MFMA GEMM
// with virtual A = h (outer) x, K = 1024*256 = 262144.
// B=1024, I2=256, H=512, N=1024 (W1||W2), J=1024.

typedef __attribute__((ext_vector_type(8))) short short8;
typedef __attribute__((ext_vector_type(4))) float f32x4;
typedef unsigned short ushort_t;

#define GLL16(gp, lp)                                                          \
  __builtin_amdgcn_global_load_lds(                                            \
      (const __attribute__((address_space(1))) void*)(gp),                     \
      (__attribute__((address_space(3))) void*)(lp), 16, 0, 0)

__device__ __forceinline__ unsigned pkbf(float a, float b) {
  __hip_bfloat162 h2 = __float22bfloat162_rn(make_float2(a, b));
  union { __hip_bfloat162 h; unsigned u; } cv;
  cv.h = h2;
  return cv.u;  // low16 = a, high16 = b
}

__device__ __forceinline__ ushort_t f2bu(float f) {
  __hip_bfloat16 b = __float2bfloat16(f);
  union { __hip_bfloat16 b; ushort_t u; } cv;
  cv.b = b;
  return cv.u;
}

// ---------------- prep: hb16[b][j], xb16[b][kx], WmergeT[l][j] (all bf16) ---
__global__ void prep_k(const float* __restrict__ in0, const float* __restrict__ in1,
                       const float* __restrict__ s0, const float* __restrict__ s1,
                       const float* __restrict__ Wm,
                       ushort_t* __restrict__ hb, ushort_t* __restrict__ xb,
                       ushort_t* __restrict__ WmT) {
  __shared__ float tl[64][65];
  const int bid = blockIdx.x, t = threadIdx.x;
  if (bid < 256) {  // hb16: 1M elems, 4096/block
#pragma unroll
    for (int i = 0; i < 4; ++i) {
      int e = bid * 4096 + i * 1024 + t * 4;
      int b = e >> 10, j = e & 1023;
      const float* src = (j < 512) ? (s0 + (size_t)b * 512 + j)
                                   : (s1 + (size_t)b * 512 + j - 512);
      float4 v = *(const float4*)src;
      ushort4 o;
      o.x = f2bu(v.x); o.y = f2bu(v.y); o.z = f2bu(v.z); o.w = f2bu(v.w);
      *(ushort4*)(hb + e) = o;
    }
  } else if (bid < 272) {  // xb16: 256K elems, 16384/block
#pragma unroll
    for (int i = 0; i < 16; ++i) {
      int e = (bid - 256) * 16384 + i * 1024 + t * 4;
      int b = e >> 8, kx = e & 255;
      const float* src = (kx < 128) ? (in0 + (size_t)b * 128 + kx)
                                    : (in1 + (size_t)b * 128 + kx - 128);
      float4 v = *(const float4*)src;
      ushort4 o;
      o.x = f2bu(v.x); o.y = f2bu(v.y); o.z = f2bu(v.z); o.w = f2bu(v.w);
      *(ushort4*)(xb + e) = o;
    }
  } else {  // Wmerge [1024][512] -> WmT [512][1024], 64x64 tiles
    int q = bid - 272;           // 0..127
    int j0 = (q >> 3) * 64;
    int l0 = (q & 7) * 64;
#pragma unroll
    for (int i = 0; i < 16; ++i) {
      int idx = i * 256 + t; int r = idx >> 6, c = idx & 63;
      tl[r][c] = Wm[(size_t)(j0 + r) * 512 + l0 + c];
    }
    __syncthreads();
#pragma unroll
    for (int i = 0; i < 16; ++i) {
      int idx = i * 256 + t; int r = idx >> 6, c = idx & 63;
      WmT[(size_t)(l0 + r) * 1024 + j0 + c] = f2bu(tl[c][r]);
    }
  }
}

// ---------------- main bilinear GEMM --------------------------------------
// grid (16 ntiles, 16 kchunks), 512 threads (8 waves), 1 block/CU.
// Block: all 1024 batch rows x 64 n-cols; K-chunk = 512 j's x 32 kx's.
// LDS: W f32 tile [64 col][8 jsub][32 kx], double buffered = 128 KB,
// filled by global_load_lds w/ source-side chunk-XOR swizzle.
// __launch_bounds__(512,1): 256-VGPR budget. acc(128)+xc(32)+hc(32)+bfr(16)
// + temps ~= 240 must NOT spill — (512,2)'s 128-cap caused 14.7 GB of
// scratch traffic and 16x slowdown (R1 post-mortem).
__global__ __launch_bounds__(512, 1) void bilin_k(
    const float* __restrict__ W1, const float* __restrict__ W2,
    const ushort_t* __restrict__ hb, const ushort_t* __restrict__ xb,
    float* __restrict__ accg) {
  __shared__ float Bl[2][16384];  // 2 x 64 KB

  const int ntile = blockIdx.x;         // 0..15 -> n cols ntile*64..+63
  const int chunk = blockIdx.y;         // 0..15
  const int kxwin = (chunk & 7) * 32;   // kx window
  const int jbase0 = (chunk >> 3) * 512;
  const int tid = threadIdx.x;
  const int wave = tid >> 6;
  const int lane = tid & 63;
  const int l15 = lane & 15;
  const int lg = lane >> 4;
  const int wrow = wave * 128;          // wave's 128 batch rows
  const int jsg = lane >> 3;            // gll: j-sub handled by this lane
  const int slot = lane & 7;            // gll: 16B slot within 32-kx run

  const float* Wsel = (ntile < 8) ? W1 : W2;
  const float* Wbase = Wsel + (size_t)(ntile & 7) * 64 * 262144;

  // per-lane x cache: 8 bf16 per M-group (j-invariant)
  uint4 xc[8];
#pragma unroll
  for (int g = 0; g < 8; ++g)
    xc[g] = *(const uint4*)(xb + (size_t)(wrow + g * 16 + l15) * 256 + kxwin + lg * 8);

  f32x4 acc[8][4];
  const f32x4 z4 = {0.f, 0.f, 0.f, 0.f};
#pragma unroll
  for (int g = 0; g < 8; ++g)
#pragma unroll
    for (int nc = 0; nc < 4; ++nc) acc[g][nc] = z4;

  // prologue: stage 0
  {
    float* dst = &Bl[0][0];
#pragma unroll
    for (int i = 0; i < 8; ++i) {
      int col = wave * 8 + i;
      const float* gp = Wbase + (size_t)col * 262144 +
                        (size_t)(jbase0 + jsg) * 256 + kxwin +
                        ((slot ^ (col & 7)) << 2);
      GLL16(gp, dst + col * 256);
    }
  }
  __syncthreads();

  for (int t = 0; t < 64; ++t) {
    const int jbase = jbase0 + t * 8;
    // h for this stage: 8 consecutive j per row, packed bf16
    uint4 hc[8];
#pragma unroll
    for (int g = 0; g < 8; ++g)
      hc[g] = *(const uint4*)(hb + (size_t)(wrow + g * 16 + l15) * 1024 + jbase);

    // prefetch next W tile (flies during compute; drained by syncthreads)
    if (t + 1 < 64) {
      float* dst = &Bl[(t + 1) & 1][0];
      const int jb2 = jbase + 8;
#pragma unroll
      for (int i = 0; i < 8; ++i) {
        int col = wave * 8 + i;
        const float* gp = Wbase + (size_t)col * 262144 +
                          (size_t)(jb2 + jsg) * 256 + kxwin +
                          ((slot ^ (col & 7)) << 2);
        GLL16(gp, dst + col * 256);
      }
    }

    const float* bp = &Bl[t & 1][0];
#pragma unroll
    for (int js = 0; js < 8; ++js) {
      // B fragments: f32 from LDS (swizzled), cvt to bf16
      short8 bfr[4];
#pragma unroll
      for (int nc = 0; nc < 4; ++nc) {
        int col = nc * 16 + l15;
        int swz = col & 7;
        int base = col * 256 + js * 32;
        float4 va = *(const float4*)(bp + base + (((lg * 2 + 0) ^ swz) << 2));
        float4 vb = *(const float4*)(bp + base + (((lg * 2 + 1) ^ swz) << 2));
        union { unsigned u[4]; short8 s; } cv;
        cv.u[0] = pkbf(va.x, va.y); cv.u[1] = pkbf(va.z, va.w);
        cv.u[2] = pkbf(vb.x, vb.y); cv.u[3] = pkbf(vb.z, vb.w);
        bfr[nc] = cv.s;
      }
#pragma unroll
      for (int g = 0; g < 8; ++g) {
        unsigned hw = (js < 2) ? hc[g].x : (js < 4) ? hc[g].y
                     : (js < 6) ? hc[g].z : hc[g].w;
        float hf = __uint_as_float((js & 1) ? (hw & 0xFFFF0000u) : (hw << 16));
        // A fragment: bf16(h * x), 8 elems
        unsigned xw[4] = {xc[g].x, xc[g].y, xc[g].z, xc[g].w};
        union { unsigned u[4]; short8 s; } av;
#pragma unroll
        for (int p = 0; p < 4; ++p) {
          float lo = __uint_as_float(xw[p] << 16);
          float hi = __uint_as_float(xw[p] & 0xFFFF0000u);
          av.u[p] = pkbf(hf * lo, hf * hi);
        }
        short8 afr = av.s;
#pragma unroll
        for (int nc = 0; nc < 4; ++nc)
          acc[g][nc] = __builtin_amdgcn_mfma_f32_16x16x32_bf16(
              afr, bfr[nc], acc[g][nc], 0, 0, 0);
      }
    }
    __syncthreads();
  }

  // epilogue: split-K accumulate (16 adds per output elem over whole grid)
#pragma unroll
  for (int g = 0; g < 8; ++g)
#pragma unroll
    for (int nc = 0; nc < 4; ++nc)
#pragma unroll
      for (int r = 0; r < 4; ++r) {
        int b = wrow + g * 16 + lg * 4 + r;
        int n = ntile * 64 + nc * 16 + l15;
        unsafeAtomicAdd(&accg[(size_t)b * 1024 + n], acc[g][nc][r]);
      }
}

// ---------------- merge = h @ Wmerge (1024x512x1024 bf16 MFMA) -------------
__device__ __forceinline__ short8 ld8bf(const ushort_t* p) {
  union { uint4 v; short8 s; } cv;
  cv.v = *(const uint4*)p;
  return cv.s;
}

__global__ __launch_bounds__(256) void merge_k(const ushort_t* __restrict__ hb,
                                               const ushort_t* __restrict__ WmT,
                                               float* __restrict__ mout) {
  const int tid = threadIdx.x;
  const int wave = tid >> 6, lane = tid & 63;
  const int l15 = lane & 15, lg = lane >> 4;
  const int m0 = blockIdx.x * 64 + (wave >> 1) * 32;
  const int n0 = blockIdx.y * 64 + (wave & 1) * 32;
  const f32x4 z4 = {0.f, 0.f, 0.f, 0.f};
  f32x4 acc[2][2];
#pragma unroll
  for (int g = 0; g < 2; ++g)
#pragma unroll
    for (int nc = 0; nc < 2; ++nc) acc[g][nc] = z4;

  for (int k = 0; k < 1024; k += 32) {
    short8 af[2], bf[2];
#pragma unroll
    for (int g = 0; g < 2; ++g)
      af[g] = ld8bf(hb + (size_t)(m0 + g * 16 + l15) * 1024 + k + lg * 8);
#pragma unroll
    for (int nc = 0; nc < 2; ++nc)
      bf[nc] = ld8bf(WmT + (size_t)(n0 + nc * 16 + l15) * 1024 + k + lg * 8);
#pragma unroll
    for (int g = 0; g < 2; ++g)
#pragma unroll
      for (int nc = 0; nc < 2; ++nc)
        acc[g][nc] = __builtin_amdgcn_mfma_f32_16x16x32_bf16(
            af[g], bf[nc], acc[g][nc], 0, 0, 0);
  }
#pragma unroll
  for (int g = 0; g < 2; ++g)
#pragma unroll
    for (int nc = 0; nc < 2; ++nc)
#pragma unroll
      for (int r = 0; r < 4; ++r)
        mout[(size_t)(m0 + g * 16 + lg * 4 + r) * 512 + n0 + nc * 16 + l15] =
            acc[g][nc][r];
}

// ---------------- finalize -------------------------------------------------
__global__ void fin_k(const float* __restrict__ accg, const float* __restrict__ mout,
                      const float* __restrict__ b1, const float* __restrict__ b2,
                      float* __restrict__ out) {
  int idx = blockIdx.x * 256 + threadIdx.x;  // 524288 total
  int b = idx >> 9, l = idx & 511;
  float m1 = accg[(size_t)b * 1024 + l];
  float m2 = accg[(size_t)b * 1024 + 512 + l];
  float st = tanhf(m1 + b1[l]);
  float u = 1.f / (1.f + expf(-(m2 + b2[l])));
  out[idx] = u * st + (1.f - u) * mout[idx];
}

extern "C" void kernel_launch(void* const* d_in, const int* in_sizes, int n_in,
                              void* d_out, int out_size, void* d_ws, size_t ws_size,
                              hipStream_t stream) {
  const float* in0 = (const float*)d_in[0];
  const float* in1 = (const float*)d_in[1];
  const float* s0  = (const float*)d_in[2];
  const float* s1  = (const float*)d_in[3];
  const float* W1  = (const float*)d_in[4];
  const float* b1  = (const float*)d_in[5];
  const float* W2  = (const float*)d_in[6];
  const float* b2  = (const float*)d_in[7];
  const float* Wm  = (const float*)d_in[8];
  float* out = (float*)d_out;

  char* ws = (char*)d_ws;
  float*    accg = (float*)(ws + 0);                          // 4 MB
  float*    mout = (float*)(ws + (4u << 20));                 // 2 MB
  ushort_t* hb   = (ushort_t*)(ws + (6u << 20));              // 2 MB
  ushort_t* xb   = (ushort_t*)(ws + (8u << 20));              // 512 KB
  ushort_t* WmT  = (ushort_t*)(ws + (8u << 20) + (512u << 10)); // 1 MB

  hipMemsetAsync(accg, 0, 4u << 20, stream);
  prep_k<<<400, 256, 0, stream>>>(in0, in1, s0, s1, Wm, hb, xb, WmT);
  bilin_k<<<dim3(16, 16), 512, 0, stream>>>(W1, W2, hb, xb, accg);
  merge_k<<<dim3(16, 8), 256, 0, stream>>>(hb, WmT, mout);
  fin_k<<<2048, 256, 0, stream>>>(accg, mout, b1, b2, out);
}

// Round 3
// 3085.355 us; speedup vs baseline: 1.3827x; 1.3465x over previous
//
#include <hip/hip_runtime.h>
#include <hip/hip_bf16.h>

// TensorizedRNN: m1/m2 = einsum('bj,bk,ljk->bl', h, x, W{1,2}) as bf16-MFMA GEMM
// with virtual A = h (outer) x, K = 1024*256 = 262144.
// B=1024, I2=256, H=512, N=1024 (W1||W2), J=1024.
//
// R3: 16-wave block, wave tile 64x64 -> acc[4][4]=64 VGPR; W staged f32 via
// global_load_lds (linear, padded), converted once to a swizzled bf16 LDS
// tile. Per-thread demand ~125 regs: MUST fit the 128-VGPR cap that caused
// R1/R2's 14.5 GB scratch thrash (the entire 4.2 ms).

typedef __attribute__((ext_vector_type(8))) short short8;
typedef __attribute__((ext_vector_type(4))) float f32x4;
typedef unsigned short ushort_t;

#define GLL16(gp, lp)                                                          \
  __builtin_amdgcn_global_load_lds(                                            \
      (const __attribute__((address_space(1))) void*)(gp),                     \
      (__attribute__((address_space(3))) void*)(lp), 16, 0, 0)

__device__ __forceinline__ unsigned pkbf(float a, float b) {
  __hip_bfloat162 h2 = __float22bfloat162_rn(make_float2(a, b));
  union { __hip_bfloat162 h; unsigned u; } cv;
  cv.h = h2;
  return cv.u;  // low16 = a, high16 = b
}

__device__ __forceinline__ ushort_t f2bu(float f) {
  __hip_bfloat16 b = __float2bfloat16(f);
  union { __hip_bfloat16 b; ushort_t u; } cv;
  cv.b = b;
  return cv.u;
}

// ---------------- prep: hb16[b][j], xb16[b][kx], WmergeT[l][j] (all bf16) ---
__global__ void prep_k(const float* __restrict__ in0, const float* __restrict__ in1,
                       const float* __restrict__ s0, const float* __restrict__ s1,
                       const float* __restrict__ Wm,
                       ushort_t* __restrict__ hb, ushort_t* __restrict__ xb,
                       ushort_t* __restrict__ WmT) {
  __shared__ float tl[64][65];
  const int bid = blockIdx.x, t = threadIdx.x;
  if (bid < 256) {  // hb16: 1M elems, 4096/block
#pragma unroll
    for (int i = 0; i < 4; ++i) {
      int e = bid * 4096 + i * 1024 + t * 4;
      int b = e >> 10, j = e & 1023;
      const float* src = (j < 512) ? (s0 + (size_t)b * 512 + j)
                                   : (s1 + (size_t)b * 512 + j - 512);
      float4 v = *(const float4*)src;
      ushort4 o;
      o.x = f2bu(v.x); o.y = f2bu(v.y); o.z = f2bu(v.z); o.w = f2bu(v.w);
      *(ushort4*)(hb + e) = o;
    }
  } else if (bid < 272) {  // xb16: 256K elems, 16384/block
#pragma unroll
    for (int i = 0; i < 16; ++i) {
      int e = (bid - 256) * 16384 + i * 1024 + t * 4;
      int b = e >> 8, kx = e & 255;
      const float* src = (kx < 128) ? (in0 + (size_t)b * 128 + kx)
                                    : (in1 + (size_t)b * 128 + kx - 128);
      float4 v = *(const float4*)src;
      ushort4 o;
      o.x = f2bu(v.x); o.y = f2bu(v.y); o.z = f2bu(v.z); o.w = f2bu(v.w);
      *(ushort4*)(xb + e) = o;
    }
  } else {  // Wmerge [1024][512] -> WmT [512][1024], 64x64 tiles
    int q = bid - 272;           // 0..127
    int j0 = (q >> 3) * 64;
    int l0 = (q & 7) * 64;
#pragma unroll
    for (int i = 0; i < 16; ++i) {
      int idx = i * 256 + t; int r = idx >> 6, c = idx & 63;
      tl[r][c] = Wm[(size_t)(j0 + r) * 512 + l0 + c];
    }
    __syncthreads();
#pragma unroll
    for (int i = 0; i < 16; ++i) {
      int idx = i * 256 + t; int r = idx >> 6, c = idx & 63;
      WmT[(size_t)(l0 + r) * 1024 + j0 + c] = f2bu(tl[c][r]);
    }
  }
}

// ---------------- main bilinear GEMM --------------------------------------
// grid (16 ntiles, 16 kchunks), 1024 threads (16 waves), 1 block/CU.
// Block: all 1024 batch rows x 64 n-cols; K-chunk = 512 j's x 32 kx's.
// Per t-stage (8 j x 32 kx = 256 K):
//   convert: stage(f32, linear+padded) -> B16(bf16, XOR-swizzled), barrier,
//   gll-prefetch W(t+1) -> stage, compute MFMA from B16, barrier.
__global__ __launch_bounds__(1024, 1) void bilin_k(
    const float* __restrict__ W1, const float* __restrict__ W2,
    const ushort_t* __restrict__ hb, const ushort_t* __restrict__ xb,
    float* __restrict__ accg) {
  __shared__ float stage[64 * 260];     // 66560 B; col stride 1040 B (pad 16B)
  __shared__ ushort_t B16[64 * 256];    // 32768 B; col stride 512 B, swizzled

  const int ntile = blockIdx.x;         // 0..15 -> n cols ntile*64..+63
  const int chunk = blockIdx.y;         // 0..15
  const int kxwin = (chunk & 7) * 32;   // kx window
  const int jbase0 = (chunk >> 3) * 512;
  const int tid = threadIdx.x;
  const int wave = tid >> 6;
  const int lane = tid & 63;
  const int l15 = lane & 15;
  const int lg = lane >> 4;
  const int wrow = wave * 64;           // wave's 64 batch rows
  const int jq = lane >> 3;             // gll: j-sub for this lane
  const int slot = lane & 7;            // gll: 16B slot within 32-kx run
  const int ccol = tid >> 4;            // convert: column 0..63
  const int cs = tid & 15;              // convert: 16B-chunk id

  const float* Wsel = (ntile < 8) ? W1 : W2;
  const float* Wbase = Wsel + (size_t)(ntile & 7) * 64 * 262144;

  // per-lane x cache: 8 bf16 per M-group (t-invariant)
  uint4 xc[4];
#pragma unroll
  for (int g = 0; g < 4; ++g)
    xc[g] = *(const uint4*)(xb + (size_t)(wrow + g * 16 + l15) * 256 + kxwin + lg * 8);

  f32x4 acc[4][4];
  const f32x4 z4 = {0.f, 0.f, 0.f, 0.f};
#pragma unroll
  for (int g = 0; g < 4; ++g)
#pragma unroll
    for (int nc = 0; nc < 4; ++nc) acc[g][nc] = z4;

  // prologue: stage W(t=0). One gll inst = one column (64 lanes x 16B = 1KB).
#pragma unroll
  for (int i = 0; i < 4; ++i) {
    int col = wave * 4 + i;
    const float* gp = Wbase + (size_t)col * 262144 +
                      (size_t)(jbase0 + jq) * 256 + kxwin + slot * 4;
    GLL16(gp, &stage[col * 260]);
  }
  __syncthreads();  // drains vmcnt(0): stage ready

  for (int t = 0; t < 64; ++t) {
    // ---- convert: stage f32 -> B16 bf16 (swizzled) ----
    {
      const float* sp = &stage[ccol * 260];
      char* bb = (char*)B16 + ccol * 512;
      int swz = (ccol & 7) << 4;
#pragma unroll
      for (int r = 0; r < 4; ++r) {
        int chunkid = cs + 16 * r;
        float4 v = *(const float4*)(sp + chunkid * 4);
        uint2 w;
        w.x = pkbf(v.x, v.y);
        w.y = pkbf(v.z, v.w);
        *(uint2*)(bb + ((chunkid * 8) ^ swz)) = w;
      }
    }
    __syncthreads();  // stage free, B16 ready

    // ---- prefetch W(t+1) into stage (async; drained by loop-end barrier) ----
    if (t < 63) {
      const int jb2 = jbase0 + (t + 1) * 8;
#pragma unroll
      for (int i = 0; i < 4; ++i) {
        int col = wave * 4 + i;
        const float* gp = Wbase + (size_t)col * 262144 +
                          (size_t)(jb2 + jq) * 256 + kxwin + slot * 4;
        GLL16(gp, &stage[col * 260]);
      }
    }

    // ---- compute: 8 j-slices x (4 bfr reads + 4 A-gens + 16 MFMA) ----
    const int jw = jbase0 + t * 8;
#pragma unroll
    for (int h = 0; h < 2; ++h) {
      uint2 hc2[4];  // h[row, jw+4h .. +3] packed bf16
#pragma unroll
      for (int g = 0; g < 4; ++g)
        hc2[g] = *(const uint2*)(hb + (size_t)(wrow + g * 16 + l15) * 1024 + jw + h * 4);
#pragma unroll
      for (int js2 = 0; js2 < 4; ++js2) {
        const int js = h * 4 + js2;
        short8 bfr[4];
#pragma unroll
        for (int nc = 0; nc < 4; ++nc) {
          int col = nc * 16 + l15;
          int byte = col * 512 + ((js * 64 + lg * 16) ^ ((col & 7) << 4));
          bfr[nc] = *(const short8*)((const char*)B16 + byte);
        }
#pragma unroll
        for (int g = 0; g < 4; ++g) {
          unsigned hwrd = (js2 < 2) ? hc2[g].x : hc2[g].y;
          float hf = __uint_as_float((js2 & 1) ? (hwrd & 0xFFFF0000u) : (hwrd << 16));
          unsigned xw[4] = {xc[g].x, xc[g].y, xc[g].z, xc[g].w};
          union { unsigned u[4]; short8 s; } av;
#pragma unroll
          for (int p = 0; p < 4; ++p) {
            float lo = __uint_as_float(xw[p] << 16);
            float hi = __uint_as_float(xw[p] & 0xFFFF0000u);
            av.u[p] = pkbf(hf * lo, hf * hi);
          }
          short8 afr = av.s;
#pragma unroll
          for (int nc = 0; nc < 4; ++nc)
            acc[g][nc] = __builtin_amdgcn_mfma_f32_16x16x32_bf16(
                afr, bfr[nc], acc[g][nc], 0, 0, 0);
        }
      }
    }
    __syncthreads();  // B16 reads done; gll(t+1) landed (vmcnt drain)
  }

  // epilogue: split-K accumulate (16 adds per output elem over whole grid)
#pragma unroll
  for (int g = 0; g < 4; ++g)
#pragma unroll
    for (int nc = 0; nc < 4; ++nc)
#pragma unroll
      for (int r = 0; r < 4; ++r) {
        int b = wrow + g * 16 + lg * 4 + r;
        int n = ntile * 64 + nc * 16 + l15;
        unsafeAtomicAdd(&accg[(size_t)b * 1024 + n], acc[g][nc][r]);
      }
}

// ---------------- merge = h @ Wmerge (1024x512x1024 bf16 MFMA) -------------
__device__ __forceinline__ short8 ld8bf(const ushort_t* p) {
  union { uint4 v; short8 s; } cv;
  cv.v = *(const uint4*)p;
  return cv.s;
}

__global__ __launch_bounds__(256) void merge_k(const ushort_t* __restrict__ hb,
                                               const ushort_t* __restrict__ WmT,
                                               float* __restrict__ mout) {
  const int tid = threadIdx.x;
  const int wave = tid >> 6, lane = tid & 63;
  const int l15 = lane & 15, lg = lane >> 4;
  const int m0 = blockIdx.x * 64 + (wave >> 1) * 32;
  const int n0 = blockIdx.y * 64 + (wave & 1) * 32;
  const f32x4 z4 = {0.f, 0.f, 0.f, 0.f};
  f32x4 acc[2][2];
#pragma unroll
  for (int g = 0; g < 2; ++g)
#pragma unroll
    for (int nc = 0; nc < 2; ++nc) acc[g][nc] = z4;

  for (int k = 0; k < 1024; k += 32) {
    short8 af[2], bf[2];
#pragma unroll
    for (int g = 0; g < 2; ++g)
      af[g] = ld8bf(hb + (size_t)(m0 + g * 16 + l15) * 1024 + k + lg * 8);
#pragma unroll
    for (int nc = 0; nc < 2; ++nc)
      bf[nc] = ld8bf(WmT + (size_t)(n0 + nc * 16 + l15) * 1024 + k + lg * 8);
#pragma unroll
    for (int g = 0; g < 2; ++g)
#pragma unroll
      for (int nc = 0; nc < 2; ++nc)
        acc[g][nc] = __builtin_amdgcn_mfma_f32_16x16x32_bf16(
            af[g], bf[nc], acc[g][nc], 0, 0, 0);
  }
#pragma unroll
  for (int g = 0; g < 2; ++g)
#pragma unroll
    for (int nc = 0; nc < 2; ++nc)
#pragma unroll
      for (int r = 0; r < 4; ++r)
        mout[(size_t)(m0 + g * 16 + lg * 4 + r) * 512 + n0 + nc * 16 + l15] =
            acc[g][nc][r];
}

// ---------------- finalize -------------------------------------------------
__global__ void fin_k(const float* __restrict__ accg, const float* __restrict__ mout,
                      const float* __restrict__ b1, const float* __restrict__ b2,
                      float* __restrict__ out) {
  int idx = blockIdx.x * 256 + threadIdx.x;  // 524288 total
  int b = idx >> 9, l = idx & 511;
  float m1 = accg[(size_t)b * 1024 + l];
  float m2 = accg[(size_t)b * 1024 + 512 + l];
  float st = tanhf(m1 + b1[l]);
  float u = 1.f / (1.f + expf(-(m2 + b2[l])));
  out[idx] = u * st + (1.f - u) * mout[idx];
}

extern "C" void kernel_launch(void* const* d_in, const int* in_sizes, int n_in,
                              void* d_out, int out_size, void* d_ws, size_t ws_size,
                              hipStream_t stream) {
  const float* in0 = (const float*)d_in[0];
  const float* in1 = (const float*)d_in[1];
  const float* s0  = (const float*)d_in[2];
  const float* s1  = (const float*)d_in[3];
  const float* W1  = (const float*)d_in[4];
  const float* b1  = (const float*)d_in[5];
  const float* W2  = (const float*)d_in[6];
  const float* b2  = (const float*)d_in[7];
  const float* Wm  = (const float*)d_in[8];
  float* out = (float*)d_out;

  char* ws = (char*)d_ws;
  float*    accg = (float*)(ws + 0);                          // 4 MB
  float*    mout = (float*)(ws + (4u << 20));                 // 2 MB
  ushort_t* hb   = (ushort_t*)(ws + (6u << 20));              // 2 MB
  ushort_t* xb   = (ushort_t*)(ws + (8u << 20));              // 512 KB
  ushort_t* WmT  = (ushort_t*)(ws + (8u << 20) + (512u << 10)); // 1 MB

  hipMemsetAsync(accg, 0, 4u << 20, stream);
  prep_k<<<400, 256, 0, stream>>>(in0, in1, s0, s1, Wm, hb, xb, WmT);
  bilin_k<<<dim3(16, 16), 1024, 0, stream>>>(W1, W2, hb, xb, accg);
  merge_k<<<dim3(16, 8), 256, 0, stream>>>(hb, WmT, mout);
  fin_k<<<2048, 256, 0, stream>>>(accg, mout, b1, b2, out);
}

// Round 4
// 1044.189 us; speedup vs baseline: 4.0857x; 2.9548x over previous
//
#include <hip/hip_runtime.h>
#include <hip/hip_bf16.h>

// TensorizedRNN: m1/m2 = einsum('bj,bk,ljk->bl', h, x, W{1,2}) as bf16-MFMA GEMM
// with virtual A = h (outer) x, K = 1024*256 = 262144.
// B=1024, I2=256, H=512, N=1024 (W1||W2), J=1024.
//
// R4: register-fit-by-construction.
//  - __launch_bounds__(1024, 4): unified reg budget = 512/4 = 128.
//    (R3 post-mortem: default heuristic granted 64 and spilled ~10 GB.)
//  - wave tile 64x32 -> acc[4][2]=32 regs; total demand ~114 < 128.
//  - reg-staged W (global->reg->cvt->ds_write), double-buffered bf16 LDS
//    tile, ONE barrier per stage; loads issued before compute (T14).
//  - LDS padded to 84 KB: forces 1 block/CU (2 blocks would halve reg cap).

typedef __attribute__((ext_vector_type(8))) short short8;
typedef __attribute__((ext_vector_type(4))) float f32x4;
typedef unsigned short ushort_t;

__device__ __forceinline__ unsigned pkbf(float a, float b) {
  __hip_bfloat162 h2 = __float22bfloat162_rn(make_float2(a, b));
  union { __hip_bfloat162 h; unsigned u; } cv;
  cv.h = h2;
  return cv.u;  // low16 = a, high16 = b
}

__device__ __forceinline__ ushort_t f2bu(float f) {
  __hip_bfloat16 b = __float2bfloat16(f);
  union { __hip_bfloat16 b; ushort_t u; } cv;
  cv.b = b;
  return cv.u;
}

// ---------------- prep: hb16[b][j], xb16[b][kx], WmergeT[l][j] (all bf16) ---
__global__ void prep_k(const float* __restrict__ in0, const float* __restrict__ in1,
                       const float* __restrict__ s0, const float* __restrict__ s1,
                       const float* __restrict__ Wm,
                       ushort_t* __restrict__ hb, ushort_t* __restrict__ xb,
                       ushort_t* __restrict__ WmT) {
  __shared__ float tl[64][65];
  const int bid = blockIdx.x, t = threadIdx.x;
  if (bid < 256) {  // hb16: 1M elems, 4096/block
#pragma unroll
    for (int i = 0; i < 4; ++i) {
      int e = bid * 4096 + i * 1024 + t * 4;
      int b = e >> 10, j = e & 1023;
      const float* src = (j < 512) ? (s0 + (size_t)b * 512 + j)
                                   : (s1 + (size_t)b * 512 + j - 512);
      float4 v = *(const float4*)src;
      ushort4 o;
      o.x = f2bu(v.x); o.y = f2bu(v.y); o.z = f2bu(v.z); o.w = f2bu(v.w);
      *(ushort4*)(hb + e) = o;
    }
  } else if (bid < 272) {  // xb16: 256K elems, 16384/block
#pragma unroll
    for (int i = 0; i < 16; ++i) {
      int e = (bid - 256) * 16384 + i * 1024 + t * 4;
      int b = e >> 8, kx = e & 255;
      const float* src = (kx < 128) ? (in0 + (size_t)b * 128 + kx)
                                    : (in1 + (size_t)b * 128 + kx - 128);
      float4 v = *(const float4*)src;
      ushort4 o;
      o.x = f2bu(v.x); o.y = f2bu(v.y); o.z = f2bu(v.z); o.w = f2bu(v.w);
      *(ushort4*)(xb + e) = o;
    }
  } else {  // Wmerge [1024][512] -> WmT [512][1024], 64x64 tiles
    int q = bid - 272;           // 0..127
    int j0 = (q >> 3) * 64;
    int l0 = (q & 7) * 64;
#pragma unroll
    for (int i = 0; i < 16; ++i) {
      int idx = i * 256 + t; int r = idx >> 6, c = idx & 63;
      tl[r][c] = Wm[(size_t)(j0 + r) * 512 + l0 + c];
    }
    __syncthreads();
#pragma unroll
    for (int i = 0; i < 16; ++i) {
      int idx = i * 256 + t; int r = idx >> 6, c = idx & 63;
      WmT[(size_t)(l0 + r) * 1024 + j0 + c] = f2bu(tl[c][r]);
    }
  }
}

// ---------------- main bilinear GEMM --------------------------------------
// grid (32 ntiles, 16 kchunks) = 512 blocks, 1024 threads (16 waves).
// Block: all 1024 batch rows x 32 n-cols; K-chunk = 512 j's x 32 kx's,
// consumed in 64 stages of 8 j (256 K-elems per stage).
// Per stage: issue W(t+1) global loads -> compute MFMA from B16[cur]
// -> cvt+ds_write W(t+1) into B16[cur^1] -> barrier.
__global__ __launch_bounds__(1024, 4) void bilin_k(
    const float* __restrict__ W1, const float* __restrict__ W2,
    const ushort_t* __restrict__ hb, const ushort_t* __restrict__ xb,
    float* __restrict__ accg) {
  // 2 x 16 KB bf16 tile + pad to 84 KB so only ONE block fits per CU
  // (a second block would halve the register cap to 64 -> spill).
  __shared__ uint4 smemv[5376];  // 86016 B

  const int ntile = blockIdx.x;         // 0..31 -> n cols ntile*32..+31
  const int chunk = blockIdx.y;         // 0..15
  const int kxwin = (chunk & 7) * 32;   // kx window
  const int jbase0 = (chunk >> 3) * 512;
  const int tid = threadIdx.x;
  const int wave = tid >> 6;
  const int lane = tid & 63;
  const int l15 = lane & 15;
  const int lg = lane >> 4;
  const int wrow = wave * 64;           // wave's 64 batch rows

  // W-staging role: col 0..31, j-sub 0..7, 8-float chunk 0..3
  const int scol = tid >> 5;
  const int sj = (tid & 31) >> 2;
  const int sc4 = tid & 3;
  const int wbyte = scol * 512 + ((sj * 64 + sc4 * 16) ^ ((scol & 7) << 4));

  const float* Wsel = (ntile < 16) ? W1 : W2;
  const float* gW = Wsel + (size_t)(ntile & 15) * 32 * 262144 +
                    (size_t)scol * 262144 + (size_t)(jbase0 + sj) * 256 +
                    kxwin + sc4 * 8;

  // per-lane x cache, unpacked to f32 (t-invariant): 32 regs
  float xf[4][8];
#pragma unroll
  for (int g = 0; g < 4; ++g) {
    uint4 xw = *(const uint4*)(xb + (size_t)(wrow + g * 16 + l15) * 256 + kxwin + lg * 8);
    unsigned w[4] = {xw.x, xw.y, xw.z, xw.w};
#pragma unroll
    for (int p = 0; p < 4; ++p) {
      xf[g][2 * p]     = __uint_as_float(w[p] << 16);
      xf[g][2 * p + 1] = __uint_as_float(w[p] & 0xFFFF0000u);
    }
  }

  f32x4 acc[4][2];
  const f32x4 z4 = {0.f, 0.f, 0.f, 0.f};
#pragma unroll
  for (int g = 0; g < 4; ++g)
#pragma unroll
    for (int nc = 0; nc < 2; ++nc) acc[g][nc] = z4;

  // prologue: stage t=0 into B16[0]
  {
    float4 wa = *(const float4*)gW;
    float4 wb = *(const float4*)(gW + 4);
    uint4 pk;
    pk.x = pkbf(wa.x, wa.y); pk.y = pkbf(wa.z, wa.w);
    pk.z = pkbf(wb.x, wb.y); pk.w = pkbf(wb.z, wb.w);
    *(uint4*)((char*)smemv + wbyte) = pk;
  }
  __syncthreads();

  int cur = 0;
  for (int t = 0; t < 64; ++t) {
    const int nxt = cur ^ 1;
    // issue next-stage W loads early; consumed after compute (latency hidden)
    float4 wa, wb;
    if (t < 63) {
      const float* gp = gW + (size_t)(t + 1) * 2048;
      wa = *(const float4*)gp;
      wb = *(const float4*)(gp + 4);
    }

    // h for this stage: 8 j's per row (16 B), 4 row-groups
    const int jw = jbase0 + t * 8;
    uint4 hc[4];
#pragma unroll
    for (int g = 0; g < 4; ++g)
      hc[g] = *(const uint4*)(hb + (size_t)(wrow + g * 16 + l15) * 1024 + jw);

    const char* rb = (const char*)smemv + cur * 16384;
#pragma unroll
    for (int js = 0; js < 8; ++js) {
      short8 bfr[2];
#pragma unroll
      for (int nc = 0; nc < 2; ++nc) {
        int col = nc * 16 + l15;
        int byte = col * 512 + ((js * 64 + lg * 16) ^ ((col & 7) << 4));
        bfr[nc] = *(const short8*)(rb + byte);
      }
#pragma unroll
      for (int g = 0; g < 4; ++g) {
        unsigned hwrd = (js < 2) ? hc[g].x : (js < 4) ? hc[g].y
                       : (js < 6) ? hc[g].z : hc[g].w;
        float hf = __uint_as_float((js & 1) ? (hwrd & 0xFFFF0000u) : (hwrd << 16));
        union { unsigned u[4]; short8 s; } av;
#pragma unroll
        for (int p = 0; p < 4; ++p)
          av.u[p] = pkbf(hf * xf[g][2 * p], hf * xf[g][2 * p + 1]);
        short8 afr = av.s;
#pragma unroll
        for (int nc = 0; nc < 2; ++nc)
          acc[g][nc] = __builtin_amdgcn_mfma_f32_16x16x32_bf16(
              afr, bfr[nc], acc[g][nc], 0, 0, 0);
      }
    }

    // write next stage (waitcnt lands here, after compute)
    if (t < 63) {
      uint4 pk;
      pk.x = pkbf(wa.x, wa.y); pk.y = pkbf(wa.z, wa.w);
      pk.z = pkbf(wb.x, wb.y); pk.w = pkbf(wb.z, wb.w);
      *(uint4*)((char*)smemv + nxt * 16384 + wbyte) = pk;
    }
    __syncthreads();
    cur = nxt;
  }

  // epilogue: split-K accumulate (16 adds per output elem over whole grid)
#pragma unroll
  for (int g = 0; g < 4; ++g)
#pragma unroll
    for (int nc = 0; nc < 2; ++nc)
#pragma unroll
      for (int r = 0; r < 4; ++r) {
        int b = wrow + g * 16 + lg * 4 + r;
        int n = ntile * 32 + nc * 16 + l15;
        unsafeAtomicAdd(&accg[(size_t)b * 1024 + n], acc[g][nc][r]);
      }
}

// ---------------- merge = h @ Wmerge (1024x512x1024 bf16 MFMA) -------------
__device__ __forceinline__ short8 ld8bf(const ushort_t* p) {
  union { uint4 v; short8 s; } cv;
  cv.v = *(const uint4*)p;
  return cv.s;
}

__global__ __launch_bounds__(256) void merge_k(const ushort_t* __restrict__ hb,
                                               const ushort_t* __restrict__ WmT,
                                               float* __restrict__ mout) {
  const int tid = threadIdx.x;
  const int wave = tid >> 6, lane = tid & 63;
  const int l15 = lane & 15, lg = lane >> 4;
  const int m0 = blockIdx.x * 64 + (wave >> 1) * 32;
  const int n0 = blockIdx.y * 64 + (wave & 1) * 32;
  const f32x4 z4 = {0.f, 0.f, 0.f, 0.f};
  f32x4 acc[2][2];
#pragma unroll
  for (int g = 0; g < 2; ++g)
#pragma unroll
    for (int nc = 0; nc < 2; ++nc) acc[g][nc] = z4;

  for (int k = 0; k < 1024; k += 32) {
    short8 af[2], bf[2];
#pragma unroll
    for (int g = 0; g < 2; ++g)
      af[g] = ld8bf(hb + (size_t)(m0 + g * 16 + l15) * 1024 + k + lg * 8);
#pragma unroll
    for (int nc = 0; nc < 2; ++nc)
      bf[nc] = ld8bf(WmT + (size_t)(n0 + nc * 16 + l15) * 1024 + k + lg * 8);
#pragma unroll
    for (int g = 0; g < 2; ++g)
#pragma unroll
      for (int nc = 0; nc < 2; ++nc)
        acc[g][nc] = __builtin_amdgcn_mfma_f32_16x16x32_bf16(
            af[g], bf[nc], acc[g][nc], 0, 0, 0);
  }
#pragma unroll
  for (int g = 0; g < 2; ++g)
#pragma unroll
    for (int nc = 0; nc < 2; ++nc)
#pragma unroll
      for (int r = 0; r < 4; ++r)
        mout[(size_t)(m0 + g * 16 + lg * 4 + r) * 512 + n0 + nc * 16 + l15] =
            acc[g][nc][r];
}

// ---------------- finalize -------------------------------------------------
__global__ void fin_k(const float* __restrict__ accg, const float* __restrict__ mout,
                      const float* __restrict__ b1, const float* __restrict__ b2,
                      float* __restrict__ out) {
  int idx = blockIdx.x * 256 + threadIdx.x;  // 524288 total
  int b = idx >> 9, l = idx & 511;
  float m1 = accg[(size_t)b * 1024 + l];
  float m2 = accg[(size_t)b * 1024 + 512 + l];
  float st = tanhf(m1 + b1[l]);
  float u = 1.f / (1.f + expf(-(m2 + b2[l])));
  out[idx] = u * st + (1.f - u) * mout[idx];
}

extern "C" void kernel_launch(void* const* d_in, const int* in_sizes, int n_in,
                              void* d_out, int out_size, void* d_ws, size_t ws_size,
                              hipStream_t stream) {
  const float* in0 = (const float*)d_in[0];
  const float* in1 = (const float*)d_in[1];
  const float* s0  = (const float*)d_in[2];
  const float* s1  = (const float*)d_in[3];
  const float* W1  = (const float*)d_in[4];
  const float* b1  = (const float*)d_in[5];
  const float* W2  = (const float*)d_in[6];
  const float* b2  = (const float*)d_in[7];
  const float* Wm  = (const float*)d_in[8];
  float* out = (float*)d_out;

  char* ws = (char*)d_ws;
  float*    accg = (float*)(ws + 0);                          // 4 MB
  float*    mout = (float*)(ws + (4u << 20));                 // 2 MB
  ushort_t* hb   = (ushort_t*)(ws + (6u << 20));              // 2 MB
  ushort_t* xb   = (ushort_t*)(ws + (8u << 20));              // 512 KB
  ushort_t* WmT  = (ushort_t*)(ws + (8u << 20) + (512u << 10)); // 1 MB

  hipMemsetAsync(accg, 0, 4u << 20, stream);
  prep_k<<<400, 256, 0, stream>>>(in0, in1, s0, s1, Wm, hb, xb, WmT);
  bilin_k<<<dim3(32, 16), 1024, 0, stream>>>(W1, W2, hb, xb, accg);
  merge_k<<<dim3(16, 8), 256, 0, stream>>>(hb, WmT, mout);
  fin_k<<<2048, 256, 0, stream>>>(accg, mout, b1, b2, out);
}

// Round 6
// 1027.763 us; speedup vs baseline: 4.1510x; 1.0160x over previous
//
#include <hip/hip_runtime.h>
#include <hip/hip_bf16.h>

// TensorizedRNN: m1/m2 = einsum('bj,bk,ljk->bl', h, x, W{1,2}) as bf16-MFMA GEMM
// with virtual A = h (outer) x, K = 1024*256 = 262144.
// B=1024, I2=256, H=512, N=1024 (W1||W2), J=1024.
//
// R6 == R5 resubmitted verbatim (R5 bench died on UnresponsiveContainer —
// infra transient, no data). R5 changes vs R4:
//  - v_cvt_pk_bf16_f32 via inline asm (1 instr / 2 elems) -- suspect
//    __float22bfloat162_rn was lowering to software RNE (~5x VALU).
//  - v_pk_mul_f32 for h*x products (halves mul count).
//  - amdgpu_waves_per_eu(4,4): same occupancy HW already runs (16 waves/CU)
//    but register budget 512/4=128 -> arch ~96 after 32 AGPR acc, killing
//    remat pressure seen at the 64-reg default.
// Pipe model per CU-stage: MFMA 4966 cyc (floor), HBM 3197, VALU ~3000,
// LDS 2048 -> MFMA-bound, bilin ~320-420 us.

typedef __attribute__((ext_vector_type(8))) short short8;
typedef __attribute__((ext_vector_type(4))) float f32x4;
typedef __attribute__((ext_vector_type(2))) float f32x2;
typedef unsigned short ushort_t;

// f32 pair -> packed bf16 (low16 = a, high16 = b), single HW instr
__device__ __forceinline__ unsigned cvtpk(float a, float b) {
  unsigned r;
  asm("v_cvt_pk_bf16_f32 %0, %1, %2" : "=v"(r) : "v"(a), "v"(b));
  return r;
}

// packed f32 multiply, single HW instr
__device__ __forceinline__ f32x2 pkmul(f32x2 a, f32x2 b) {
  f32x2 r;
  asm("v_pk_mul_f32 %0, %1, %2" : "=v"(r) : "v"(a), "v"(b));
  return r;
}

__device__ __forceinline__ ushort_t f2bu(float f) {
  __hip_bfloat16 b = __float2bfloat16(f);
  union { __hip_bfloat16 b; ushort_t u; } cv;
  cv.b = b;
  return cv.u;
}

// ---------------- prep: hb16[b][j], xb16[b][kx], WmergeT[l][j] (all bf16) ---
__global__ void prep_k(const float* __restrict__ in0, const float* __restrict__ in1,
                       const float* __restrict__ s0, const float* __restrict__ s1,
                       const float* __restrict__ Wm,
                       ushort_t* __restrict__ hb, ushort_t* __restrict__ xb,
                       ushort_t* __restrict__ WmT) {
  __shared__ float tl[64][65];
  const int bid = blockIdx.x, t = threadIdx.x;
  if (bid < 256) {  // hb16: 1M elems, 4096/block
#pragma unroll
    for (int i = 0; i < 4; ++i) {
      int e = bid * 4096 + i * 1024 + t * 4;
      int b = e >> 10, j = e & 1023;
      const float* src = (j < 512) ? (s0 + (size_t)b * 512 + j)
                                   : (s1 + (size_t)b * 512 + j - 512);
      float4 v = *(const float4*)src;
      ushort4 o;
      o.x = f2bu(v.x); o.y = f2bu(v.y); o.z = f2bu(v.z); o.w = f2bu(v.w);
      *(ushort4*)(hb + e) = o;
    }
  } else if (bid < 272) {  // xb16: 256K elems, 16384/block
#pragma unroll
    for (int i = 0; i < 16; ++i) {
      int e = (bid - 256) * 16384 + i * 1024 + t * 4;
      int b = e >> 8, kx = e & 255;
      const float* src = (kx < 128) ? (in0 + (size_t)b * 128 + kx)
                                    : (in1 + (size_t)b * 128 + kx - 128);
      float4 v = *(const float4*)src;
      ushort4 o;
      o.x = f2bu(v.x); o.y = f2bu(v.y); o.z = f2bu(v.z); o.w = f2bu(v.w);
      *(ushort4*)(xb + e) = o;
    }
  } else {  // Wmerge [1024][512] -> WmT [512][1024], 64x64 tiles
    int q = bid - 272;           // 0..127
    int j0 = (q >> 3) * 64;
    int l0 = (q & 7) * 64;
#pragma unroll
    for (int i = 0; i < 16; ++i) {
      int idx = i * 256 + t; int r = idx >> 6, c = idx & 63;
      tl[r][c] = Wm[(size_t)(j0 + r) * 512 + l0 + c];
    }
    __syncthreads();
#pragma unroll
    for (int i = 0; i < 16; ++i) {
      int idx = i * 256 + t; int r = idx >> 6, c = idx & 63;
      WmT[(size_t)(l0 + r) * 1024 + j0 + c] = f2bu(tl[c][r]);
    }
  }
}

// ---------------- main bilinear GEMM --------------------------------------
// grid (32 ntiles, 16 kchunks) = 512 blocks, 1024 threads (16 waves).
// Block: all 1024 batch rows x 32 n-cols; K-chunk = 512 j's x 32 kx's,
// consumed in 64 stages of 8 j (256 K-elems per stage).
// Per stage: issue W(t+1) global loads -> compute MFMA from B16[cur]
// -> cvt+ds_write W(t+1) into B16[cur^1] -> barrier.
__global__ __launch_bounds__(1024)
__attribute__((amdgpu_waves_per_eu(4, 4))) void bilin_k(
    const float* __restrict__ W1, const float* __restrict__ W2,
    const ushort_t* __restrict__ hb, const ushort_t* __restrict__ xb,
    float* __restrict__ accg) {
  // 2 x 16 KB bf16 tile + pad to 84 KB so only ONE block fits per CU.
  __shared__ uint4 smemv[5376];  // 86016 B

  const int ntile = blockIdx.x;         // 0..31 -> n cols ntile*32..+31
  const int chunk = blockIdx.y;         // 0..15
  const int kxwin = (chunk & 7) * 32;   // kx window
  const int jbase0 = (chunk >> 3) * 512;
  const int tid = threadIdx.x;
  const int wave = tid >> 6;
  const int lane = tid & 63;
  const int l15 = lane & 15;
  const int lg = lane >> 4;
  const int wrow = wave * 64;           // wave's 64 batch rows

  // W-staging role: col 0..31, j-sub 0..7, 8-float chunk 0..3
  const int scol = tid >> 5;
  const int sj = (tid & 31) >> 2;
  const int sc4 = tid & 3;
  const int wbyte = scol * 512 + ((sj * 64 + sc4 * 16) ^ ((scol & 7) << 4));

  const float* Wsel = (ntile < 16) ? W1 : W2;
  const float* gW = Wsel + (size_t)(ntile & 15) * 32 * 262144 +
                    (size_t)scol * 262144 + (size_t)(jbase0 + sj) * 256 +
                    kxwin + sc4 * 8;

  // per-lane x cache, unpacked to f32 pairs (t-invariant): 32 regs
  f32x2 xf[4][4];
#pragma unroll
  for (int g = 0; g < 4; ++g) {
    uint4 xw = *(const uint4*)(xb + (size_t)(wrow + g * 16 + l15) * 256 + kxwin + lg * 8);
    unsigned w[4] = {xw.x, xw.y, xw.z, xw.w};
#pragma unroll
    for (int p = 0; p < 4; ++p) {
      xf[g][p][0] = __uint_as_float(w[p] << 16);
      xf[g][p][1] = __uint_as_float(w[p] & 0xFFFF0000u);
    }
  }

  f32x4 acc[4][2];
  const f32x4 z4 = {0.f, 0.f, 0.f, 0.f};
#pragma unroll
  for (int g = 0; g < 4; ++g)
#pragma unroll
    for (int nc = 0; nc < 2; ++nc) acc[g][nc] = z4;

  // prologue: stage t=0 into B16[0]
  {
    float4 wa = *(const float4*)gW;
    float4 wb = *(const float4*)(gW + 4);
    uint4 pk;
    pk.x = cvtpk(wa.x, wa.y); pk.y = cvtpk(wa.z, wa.w);
    pk.z = cvtpk(wb.x, wb.y); pk.w = cvtpk(wb.z, wb.w);
    *(uint4*)((char*)smemv + wbyte) = pk;
  }
  __syncthreads();

  int cur = 0;
  for (int t = 0; t < 64; ++t) {
    const int nxt = cur ^ 1;
    // issue next-stage W loads early; consumed after compute (latency hidden)
    float4 wa, wb;
    if (t < 63) {
      const float* gp = gW + (size_t)(t + 1) * 2048;
      wa = *(const float4*)gp;
      wb = *(const float4*)(gp + 4);
    }

    // h for this stage: 8 j's per row (16 B), 4 row-groups
    const int jw = jbase0 + t * 8;
    uint4 hc[4];
#pragma unroll
    for (int g = 0; g < 4; ++g)
      hc[g] = *(const uint4*)(hb + (size_t)(wrow + g * 16 + l15) * 1024 + jw);

    const char* rb = (const char*)smemv + cur * 16384;
#pragma unroll
    for (int js = 0; js < 8; ++js) {
      short8 bfr[2];
#pragma unroll
      for (int nc = 0; nc < 2; ++nc) {
        int col = nc * 16 + l15;
        int byte = col * 512 + ((js * 64 + lg * 16) ^ ((col & 7) << 4));
        bfr[nc] = *(const short8*)(rb + byte);
      }
#pragma unroll
      for (int g = 0; g < 4; ++g) {
        unsigned hwrd = (js < 2) ? hc[g].x : (js < 4) ? hc[g].y
                       : (js < 6) ? hc[g].z : hc[g].w;
        float hf = __uint_as_float((js & 1) ? (hwrd & 0xFFFF0000u) : (hwrd << 16));
        f32x2 hf2; hf2[0] = hf; hf2[1] = hf;
        union { unsigned u[4]; short8 s; } av;
#pragma unroll
        for (int p = 0; p < 4; ++p) {
          f32x2 m = pkmul(xf[g][p], hf2);
          av.u[p] = cvtpk(m[0], m[1]);
        }
        short8 afr = av.s;
#pragma unroll
        for (int nc = 0; nc < 2; ++nc)
          acc[g][nc] = __builtin_amdgcn_mfma_f32_16x16x32_bf16(
              afr, bfr[nc], acc[g][nc], 0, 0, 0);
      }
    }

    // write next stage (waitcnt lands here, after compute)
    if (t < 63) {
      uint4 pk;
      pk.x = cvtpk(wa.x, wa.y); pk.y = cvtpk(wa.z, wa.w);
      pk.z = cvtpk(wb.x, wb.y); pk.w = cvtpk(wb.z, wb.w);
      *(uint4*)((char*)smemv + nxt * 16384 + wbyte) = pk;
    }
    __syncthreads();
    cur = nxt;
  }

  // epilogue: split-K accumulate (16 adds per output elem over whole grid)
#pragma unroll
  for (int g = 0; g < 4; ++g)
#pragma unroll
    for (int nc = 0; nc < 2; ++nc)
#pragma unroll
      for (int r = 0; r < 4; ++r) {
        int b = wrow + g * 16 + lg * 4 + r;
        int n = ntile * 32 + nc * 16 + l15;
        unsafeAtomicAdd(&accg[(size_t)b * 1024 + n], acc[g][nc][r]);
      }
}

// ---------------- merge = h @ Wmerge (1024x512x1024 bf16 MFMA) -------------
__device__ __forceinline__ short8 ld8bf(const ushort_t* p) {
  union { uint4 v; short8 s; } cv;
  cv.v = *(const uint4*)p;
  return cv.s;
}

__global__ __launch_bounds__(256) void merge_k(const ushort_t* __restrict__ hb,
                                               const ushort_t* __restrict__ WmT,
                                               float* __restrict__ mout) {
  const int tid = threadIdx.x;
  const int wave = tid >> 6, lane = tid & 63;
  const int l15 = lane & 15, lg = lane >> 4;
  const int m0 = blockIdx.x * 64 + (wave >> 1) * 32;
  const int n0 = blockIdx.y * 64 + (wave & 1) * 32;
  const f32x4 z4 = {0.f, 0.f, 0.f, 0.f};
  f32x4 acc[2][2];
#pragma unroll
  for (int g = 0; g < 2; ++g)
#pragma unroll
    for (int nc = 0; nc < 2; ++nc) acc[g][nc] = z4;

  for (int k = 0; k < 1024; k += 32) {
    short8 af[2], bf[2];
#pragma unroll
    for (int g = 0; g < 2; ++g)
      af[g] = ld8bf(hb + (size_t)(m0 + g * 16 + l15) * 1024 + k + lg * 8);
#pragma unroll
    for (int nc = 0; nc < 2; ++nc)
      bf[nc] = ld8bf(WmT + (size_t)(n0 + nc * 16 + l15) * 1024 + k + lg * 8);
#pragma unroll
    for (int g = 0; g < 2; ++g)
#pragma unroll
      for (int nc = 0; nc < 2; ++nc)
        acc[g][nc] = __builtin_amdgcn_mfma_f32_16x16x32_bf16(
            af[g], bf[nc], acc[g][nc], 0, 0, 0);
  }
#pragma unroll
  for (int g = 0; g < 2; ++g)
#pragma unroll
    for (int nc = 0; nc < 2; ++nc)
#pragma unroll
      for (int r = 0; r < 4; ++r)
        mout[(size_t)(m0 + g * 16 + lg * 4 + r) * 512 + n0 + nc * 16 + l15] =
            acc[g][nc][r];
}

// ---------------- finalize -------------------------------------------------
__global__ void fin_k(const float* __restrict__ accg, const float* __restrict__ mout,
                      const float* __restrict__ b1, const float* __restrict__ b2,
                      float* __restrict__ out) {
  int idx = blockIdx.x * 256 + threadIdx.x;  // 524288 total
  int b = idx >> 9, l = idx & 511;
  float m1 = accg[(size_t)b * 1024 + l];
  float m2 = accg[(size_t)b * 1024 + 512 + l];
  float st = tanhf(m1 + b1[l]);
  float u = 1.f / (1.f + expf(-(m2 + b2[l])));
  out[idx] = u * st + (1.f - u) * mout[idx];
}

extern "C" void kernel_launch(void* const* d_in, const int* in_sizes, int n_in,
                              void* d_out, int out_size, void* d_ws, size_t ws_size,
                              hipStream_t stream) {
  const float* in0 = (const float*)d_in[0];
  const float* in1 = (const float*)d_in[1];
  const float* s0  = (const float*)d_in[2];
  const float* s1  = (const float*)d_in[3];
  const float* W1  = (const float*)d_in[4];
  const float* b1  = (const float*)d_in[5];
  const float* W2  = (const float*)d_in[6];
  const float* b2  = (const float*)d_in[7];
  const float* Wm  = (const float*)d_in[8];
  float* out = (float*)d_out;

  char* ws = (char*)d_ws;
  float*    accg = (float*)(ws + 0);                          // 4 MB
  float*    mout = (float*)(ws + (4u << 20));                 // 2 MB
  ushort_t* hb   = (ushort_t*)(ws + (6u << 20));              // 2 MB
  ushort_t* xb   = (ushort_t*)(ws + (8u << 20));              // 512 KB
  ushort_t* WmT  = (ushort_t*)(ws + (8u << 20) + (512u << 10)); // 1 MB

  hipMemsetAsync(accg, 0, 4u << 20, stream);
  prep_k<<<400, 256, 0, stream>>>(in0, in1, s0, s1, Wm, hb, xb, WmT);
  bilin_k<<<dim3(32, 16), 1024, 0, stream>>>(W1, W2, hb, xb, accg);
  merge_k<<<dim3(16, 8), 256, 0, stream>>>(hb, WmT, mout);
  fin_k<<<2048, 256, 0, stream>>>(accg, mout, b1, b2, out);
}

// Round 9
// 797.231 us; speedup vs baseline: 5.3513x; 1.2892x over previous
//
#include <hip/hip_runtime.h>
#include <hip/hip_bf16.h>

// TensorizedRNN: m1/m2 = einsum('bj,bk,ljk->bl', h, x, W{1,2}) as bf16-MFMA GEMM
// with virtual A = h (outer) x, K = 1024*256 = 262144.
// B=1024, I2=256, H=512, N=1024 (W1||W2), J=1024.
//
// R9 == R7/R8 resubmitted verbatim (R7+R8 benches died on UnresponsiveContainer
// on the same flapping pod — connection closed before push; no data either
// time; R6 with identical-family source ran fine). R7 changes vs R6:
//  - bfr[2][2] register double-buffer: ds_read js+1 issued during js compute
//    (at the 64-reg schedule the compiler was issuing ds_read just-in-time,
//    exposing ~120cy LDS latency per js iteration).
//  - s_setprio(1) around per-js compute burst.
//  - xf unpacked (pkmul path); budget ~120 combined regs under (4,4)'s 128.
// R6 evidence: VALU cut 55->34.5% with zero dur change; MfmaUtil 21.7% =
// pure MFMA work / wall; ~60% stall. 498 TF == the 2-phase-schedule regime.

typedef __attribute__((ext_vector_type(8))) short short8;
typedef __attribute__((ext_vector_type(4))) float f32x4;
typedef __attribute__((ext_vector_type(2))) float f32x2;
typedef unsigned short ushort_t;

// f32 pair -> packed bf16 (low16 = a, high16 = b), single HW instr
__device__ __forceinline__ unsigned cvtpk(float a, float b) {
  unsigned r;
  asm("v_cvt_pk_bf16_f32 %0, %1, %2" : "=v"(r) : "v"(a), "v"(b));
  return r;
}

// packed f32 multiply, single HW instr
__device__ __forceinline__ f32x2 pkmul(f32x2 a, f32x2 b) {
  f32x2 r;
  asm("v_pk_mul_f32 %0, %1, %2" : "=v"(r) : "v"(a), "v"(b));
  return r;
}

__device__ __forceinline__ ushort_t f2bu(float f) {
  __hip_bfloat16 b = __float2bfloat16(f);
  union { __hip_bfloat16 b; ushort_t u; } cv;
  cv.b = b;
  return cv.u;
}

// ---------------- prep: hb16[b][j], xb16[b][kx], WmergeT[l][j] (all bf16) ---
__global__ void prep_k(const float* __restrict__ in0, const float* __restrict__ in1,
                       const float* __restrict__ s0, const float* __restrict__ s1,
                       const float* __restrict__ Wm,
                       ushort_t* __restrict__ hb, ushort_t* __restrict__ xb,
                       ushort_t* __restrict__ WmT) {
  __shared__ float tl[64][65];
  const int bid = blockIdx.x, t = threadIdx.x;
  if (bid < 256) {  // hb16: 1M elems, 4096/block
#pragma unroll
    for (int i = 0; i < 4; ++i) {
      int e = bid * 4096 + i * 1024 + t * 4;
      int b = e >> 10, j = e & 1023;
      const float* src = (j < 512) ? (s0 + (size_t)b * 512 + j)
                                   : (s1 + (size_t)b * 512 + j - 512);
      float4 v = *(const float4*)src;
      ushort4 o;
      o.x = f2bu(v.x); o.y = f2bu(v.y); o.z = f2bu(v.z); o.w = f2bu(v.w);
      *(ushort4*)(hb + e) = o;
    }
  } else if (bid < 272) {  // xb16: 256K elems, 16384/block
#pragma unroll
    for (int i = 0; i < 16; ++i) {
      int e = (bid - 256) * 16384 + i * 1024 + t * 4;
      int b = e >> 8, kx = e & 255;
      const float* src = (kx < 128) ? (in0 + (size_t)b * 128 + kx)
                                    : (in1 + (size_t)b * 128 + kx - 128);
      float4 v = *(const float4*)src;
      ushort4 o;
      o.x = f2bu(v.x); o.y = f2bu(v.y); o.z = f2bu(v.z); o.w = f2bu(v.w);
      *(ushort4*)(xb + e) = o;
    }
  } else {  // Wmerge [1024][512] -> WmT [512][1024], 64x64 tiles
    int q = bid - 272;           // 0..127
    int j0 = (q >> 3) * 64;
    int l0 = (q & 7) * 64;
#pragma unroll
    for (int i = 0; i < 16; ++i) {
      int idx = i * 256 + t; int r = idx >> 6, c = idx & 63;
      tl[r][c] = Wm[(size_t)(j0 + r) * 512 + l0 + c];
    }
    __syncthreads();
#pragma unroll
    for (int i = 0; i < 16; ++i) {
      int idx = i * 256 + t; int r = idx >> 6, c = idx & 63;
      WmT[(size_t)(l0 + r) * 1024 + j0 + c] = f2bu(tl[c][r]);
    }
  }
}

// ---------------- main bilinear GEMM --------------------------------------
// grid (32 ntiles, 16 kchunks) = 512 blocks, 1024 threads (16 waves).
// Block: all 1024 batch rows x 32 n-cols; K-chunk = 512 j's x 32 kx's,
// consumed in 64 stages of 8 j (256 K-elems per stage).
// Per stage: issue W(t+1) global loads -> compute MFMA from B16[cur]
// (with register-pipelined bfr) -> cvt+ds_write W(t+1) -> barrier.
__global__ __launch_bounds__(1024)
__attribute__((amdgpu_waves_per_eu(4, 4))) void bilin_k(
    const float* __restrict__ W1, const float* __restrict__ W2,
    const ushort_t* __restrict__ hb, const ushort_t* __restrict__ xb,
    float* __restrict__ accg) {
  // 2 x 16 KB bf16 tile + pad to 84 KB so only ONE block fits per CU.
  __shared__ uint4 smemv[5376];  // 86016 B

  const int ntile = blockIdx.x;         // 0..31 -> n cols ntile*32..+31
  const int chunk = blockIdx.y;         // 0..15
  const int kxwin = (chunk & 7) * 32;   // kx window
  const int jbase0 = (chunk >> 3) * 512;
  const int tid = threadIdx.x;
  const int wave = tid >> 6;
  const int lane = tid & 63;
  const int l15 = lane & 15;
  const int lg = lane >> 4;
  const int wrow = wave * 64;           // wave's 64 batch rows

  // W-staging role: col 0..31, j-sub 0..7, 8-float chunk 0..3
  const int scol = tid >> 5;
  const int sj = (tid & 31) >> 2;
  const int sc4 = tid & 3;
  const int wbyte = scol * 512 + ((sj * 64 + sc4 * 16) ^ ((scol & 7) << 4));

  const float* Wsel = (ntile < 16) ? W1 : W2;
  const float* gW = Wsel + (size_t)(ntile & 15) * 32 * 262144 +
                    (size_t)scol * 262144 + (size_t)(jbase0 + sj) * 256 +
                    kxwin + sc4 * 8;

  // per-lane x cache, unpacked to f32 pairs (t-invariant): 32 regs
  f32x2 xf[4][4];
#pragma unroll
  for (int g = 0; g < 4; ++g) {
    uint4 xw = *(const uint4*)(xb + (size_t)(wrow + g * 16 + l15) * 256 + kxwin + lg * 8);
    unsigned w[4] = {xw.x, xw.y, xw.z, xw.w};
#pragma unroll
    for (int p = 0; p < 4; ++p) {
      xf[g][p][0] = __uint_as_float(w[p] << 16);
      xf[g][p][1] = __uint_as_float(w[p] & 0xFFFF0000u);
    }
  }

  f32x4 acc[4][2];
  const f32x4 z4 = {0.f, 0.f, 0.f, 0.f};
#pragma unroll
  for (int g = 0; g < 4; ++g)
#pragma unroll
    for (int nc = 0; nc < 2; ++nc) acc[g][nc] = z4;

  // prologue: stage t=0 into B16[0]
  {
    float4 wa = *(const float4*)gW;
    float4 wb = *(const float4*)(gW + 4);
    uint4 pk;
    pk.x = cvtpk(wa.x, wa.y); pk.y = cvtpk(wa.z, wa.w);
    pk.z = cvtpk(wb.x, wb.y); pk.w = cvtpk(wb.z, wb.w);
    *(uint4*)((char*)smemv + wbyte) = pk;
  }
  __syncthreads();

  int cur = 0;
  for (int t = 0; t < 64; ++t) {
    const int nxt = cur ^ 1;
    // issue next-stage W loads early; consumed after compute (latency hidden)
    float4 wa, wb;
    if (t < 63) {
      const float* gp = gW + (size_t)(t + 1) * 2048;
      wa = *(const float4*)gp;
      wb = *(const float4*)(gp + 4);
    }

    // h for this stage: 8 j's per row (16 B), 4 row-groups
    const int jw = jbase0 + t * 8;
    uint4 hc[4];
#pragma unroll
    for (int g = 0; g < 4; ++g)
      hc[g] = *(const uint4*)(hb + (size_t)(wrow + g * 16 + l15) * 1024 + jw);

    const char* rb = (const char*)smemv + cur * 16384;

    // register double-buffer for B fragments: preload js=0
    short8 bfr[2][2];
#pragma unroll
    for (int nc = 0; nc < 2; ++nc) {
      int col = nc * 16 + l15;
      int byte = col * 512 + ((lg * 16) ^ ((col & 7) << 4));
      bfr[0][nc] = *(const short8*)(rb + byte);
    }

#pragma unroll
    for (int js = 0; js < 8; ++js) {
      const int pb = js & 1, nb = pb ^ 1;
      // prefetch js+1's B fragments (independent of this js's MFMAs)
      if (js < 7) {
#pragma unroll
        for (int nc = 0; nc < 2; ++nc) {
          int col = nc * 16 + l15;
          int byte = col * 512 + (((js + 1) * 64 + lg * 16) ^ ((col & 7) << 4));
          bfr[nb][nc] = *(const short8*)(rb + byte);
        }
      }
      __builtin_amdgcn_s_setprio(1);
#pragma unroll
      for (int g = 0; g < 4; ++g) {
        unsigned hwrd = (js < 2) ? hc[g].x : (js < 4) ? hc[g].y
                       : (js < 6) ? hc[g].z : hc[g].w;
        float hf = __uint_as_float((js & 1) ? (hwrd & 0xFFFF0000u) : (hwrd << 16));
        f32x2 hf2; hf2[0] = hf; hf2[1] = hf;
        union { unsigned u[4]; short8 s; } av;
#pragma unroll
        for (int p = 0; p < 4; ++p) {
          f32x2 m = pkmul(xf[g][p], hf2);
          av.u[p] = cvtpk(m[0], m[1]);
        }
        short8 afr = av.s;
#pragma unroll
        for (int nc = 0; nc < 2; ++nc)
          acc[g][nc] = __builtin_amdgcn_mfma_f32_16x16x32_bf16(
              afr, bfr[pb][nc], acc[g][nc], 0, 0, 0);
      }
      __builtin_amdgcn_s_setprio(0);
    }

    // write next stage (waitcnt lands here, after compute)
    if (t < 63) {
      uint4 pk;
      pk.x = cvtpk(wa.x, wa.y); pk.y = cvtpk(wa.z, wa.w);
      pk.z = cvtpk(wb.x, wb.y); pk.w = cvtpk(wb.z, wb.w);
      *(uint4*)((char*)smemv + nxt * 16384 + wbyte) = pk;
    }
    __syncthreads();
    cur = nxt;
  }

  // epilogue: split-K accumulate (16 adds per output elem over whole grid)
#pragma unroll
  for (int g = 0; g < 4; ++g)
#pragma unroll
    for (int nc = 0; nc < 2; ++nc)
#pragma unroll
      for (int r = 0; r < 4; ++r) {
        int b = wrow + g * 16 + lg * 4 + r;
        int n = ntile * 32 + nc * 16 + l15;
        unsafeAtomicAdd(&accg[(size_t)b * 1024 + n], acc[g][nc][r]);
      }
}

// ---------------- merge = h @ Wmerge (1024x512x1024 bf16 MFMA) -------------
__device__ __forceinline__ short8 ld8bf(const ushort_t* p) {
  union { uint4 v; short8 s; } cv;
  cv.v = *(const uint4*)p;
  return cv.s;
}

__global__ __launch_bounds__(256) void merge_k(const ushort_t* __restrict__ hb,
                                               const ushort_t* __restrict__ WmT,
                                               float* __restrict__ mout) {
  const int tid = threadIdx.x;
  const int wave = tid >> 6, lane = tid & 63;
  const int l15 = lane & 15, lg = lane >> 4;
  const int m0 = blockIdx.x * 64 + (wave >> 1) * 32;
  const int n0 = blockIdx.y * 64 + (wave & 1) * 32;
  const f32x4 z4 = {0.f, 0.f, 0.f, 0.f};
  f32x4 acc[2][2];
#pragma unroll
  for (int g = 0; g < 2; ++g)
#pragma unroll
    for (int nc = 0; nc < 2; ++nc) acc[g][nc] = z4;

  for (int k = 0; k < 1024; k += 32) {
    short8 af[2], bf[2];
#pragma unroll
    for (int g = 0; g < 2; ++g)
      af[g] = ld8bf(hb + (size_t)(m0 + g * 16 + l15) * 1024 + k + lg * 8);
#pragma unroll
    for (int nc = 0; nc < 2; ++nc)
      bf[nc] = ld8bf(WmT + (size_t)(n0 + nc * 16 + l15) * 1024 + k + lg * 8);
#pragma unroll
    for (int g = 0; g < 2; ++g)
#pragma unroll
      for (int nc = 0; nc < 2; ++nc)
        acc[g][nc] = __builtin_amdgcn_mfma_f32_16x16x32_bf16(
            af[g], bf[nc], acc[g][nc], 0, 0, 0);
  }
#pragma unroll
  for (int g = 0; g < 2; ++g)
#pragma unroll
    for (int nc = 0; nc < 2; ++nc)
#pragma unroll
      for (int r = 0; r < 4; ++r)
        mout[(size_t)(m0 + g * 16 + lg * 4 + r) * 512 + n0 + nc * 16 + l15] =
            acc[g][nc][r];
}

// ---------------- finalize -------------------------------------------------
__global__ void fin_k(const float* __restrict__ accg, const float* __restrict__ mout,
                      const float* __restrict__ b1, const float* __restrict__ b2,
                      float* __restrict__ out) {
  int idx = blockIdx.x * 256 + threadIdx.x;  // 524288 total
  int b = idx >> 9, l = idx & 511;
  float m1 = accg[(size_t)b * 1024 + l];
  float m2 = accg[(size_t)b * 1024 + 512 + l];
  float st = tanhf(m1 + b1[l]);
  float u = 1.f / (1.f + expf(-(m2 + b2[l])));
  out[idx] = u * st + (1.f - u) * mout[idx];
}

extern "C" void kernel_launch(void* const* d_in, const int* in_sizes, int n_in,
                              void* d_out, int out_size, void* d_ws, size_t ws_size,
                              hipStream_t stream) {
  const float* in0 = (const float*)d_in[0];
  const float* in1 = (const float*)d_in[1];
  const float* s0  = (const float*)d_in[2];
  const float* s1  = (const float*)d_in[3];
  const float* W1  = (const float*)d_in[4];
  const float* b1  = (const float*)d_in[5];
  const float* W2  = (const float*)d_in[6];
  const float* b2  = (const float*)d_in[7];
  const float* Wm  = (const float*)d_in[8];
  float* out = (float*)d_out;

  char* ws = (char*)d_ws;
  float*    accg = (float*)(ws + 0);                          // 4 MB
  float*    mout = (float*)(ws + (4u << 20));                 // 2 MB
  ushort_t* hb   = (ushort_t*)(ws + (6u << 20));              // 2 MB
  ushort_t* xb   = (ushort_t*)(ws + (8u << 20));              // 512 KB
  ushort_t* WmT  = (ushort_t*)(ws + (8u << 20) + (512u << 10)); // 1 MB

  hipMemsetAsync(accg, 0, 4u << 20, stream);
  prep_k<<<400, 256, 0, stream>>>(in0, in1, s0, s1, Wm, hb, xb, WmT);
  bilin_k<<<dim3(32, 16), 1024, 0, stream>>>(W1, W2, hb, xb, accg);
  merge_k<<<dim3(16, 8), 256, 0, stream>>>(hb, WmT, mout);
  fin_k<<<2048, 256, 0, stream>>>(accg, mout, b1, b2, out);
}